// Round 6
// baseline (249.949 us; speedup 1.0000x reference)
//
#include <hip/hip_runtime.h>
#include <math.h>

#define NB 256
#define NF 8
#define NS 200
#define ND 64
#define NH 36
#define EPSV 1e-3f
#define GRID_BLKS 256   // 1 block/CU guaranteed resident -> barrier safe

// ws float-offset layout: [0,288) sum | [288,576) sumsq | 576 barrier counter
#define WS_SUM 0
#define WS_SQ  288
#define WS_BAR 576

typedef __attribute__((ext_vector_type(8))) short short8;
typedef __attribute__((ext_vector_type(4))) float f32x4;
typedef __attribute__((ext_vector_type(4))) int int4v;

__device__ __forceinline__ unsigned short f32_to_bf16_rne(float x) {
    unsigned u = __float_as_uint(x);
    unsigned r = u + 0x7FFFu + ((u >> 16) & 1u);
    return (unsigned short)(r >> 16);
}
__device__ __forceinline__ float bf16_to_f32(unsigned short h) {
    return __uint_as_float(((unsigned)h) << 16);
}
// 8 floats -> 8 bf16 (truncation) via 4 v_perm_b32 (validated rounds 4).
__device__ __forceinline__ short8 pack8(float4 a, float4 b) {
    int4v t;
    t[0] = (int)__builtin_amdgcn_perm(__float_as_uint(a.y), __float_as_uint(a.x), 0x07060302u);
    t[1] = (int)__builtin_amdgcn_perm(__float_as_uint(a.w), __float_as_uint(a.z), 0x07060302u);
    t[2] = (int)__builtin_amdgcn_perm(__float_as_uint(b.y), __float_as_uint(b.x), 0x07060302u);
    t[3] = (int)__builtin_amdgcn_perm(__float_as_uint(b.w), __float_as_uint(b.z), 0x07060302u);
    return __builtin_bit_cast(short8, t);
}

__global__ __launch_bounds__(512, 2) void k_fused(
    const float* __restrict__ query, const float* __restrict__ key,
    const float* __restrict__ W_h, const float* __restrict__ b_h,
    const float* __restrict__ alpha, const float* __restrict__ W_o,
    const float* __restrict__ b_o, const int* __restrict__ seqn,
    float* __restrict__ ws, float* __restrict__ out)
{
    const int blk = blockIdx.x;
    const int f = blk & (NF - 1);
    const int b0 = (blk >> 3) * 8;        // 8 batches per block
    const int tid = threadIdx.x;
    const int lane = tid & 63;
    const int wv = tid >> 6;              // 8 waves
    const int col = lane & 15;
    const int quad = lane >> 4;

    __shared__ __align__(16) unsigned short wkL[48 * 72];
    __shared__ float qs[8][64];
    __shared__ float qts[8][48];
    __shared__ float sumP[48], sqP[48];
    __shared__ float sw[208];
    __shared__ float redM[8], redS[8];
    __shared__ float pout[8][64];

    const float* Wf = W_h + (size_t)f * (3 * ND * NH);
    const size_t bstride = (size_t)NF * NS * ND;
    const float* kb0 = key + (size_t)(b0 * NF + f) * (NS * ND);

    // ---- prologue stage 1: query rows, WkT->LDS(bf16), zero partials ----
    {
        int p = tid >> 6, d = tid & 63;
        qs[p][d] = query[(size_t)((b0 + p) * NF + f) * ND + d];
    }
    for (int i = tid; i < 48 * 64; i += 512) {
        int h = i >> 6, d = i & 63;
        float v = (h < NH) ? (Wf[d * NH + h] - Wf[(2 * ND + d) * NH + h]) : 0.f;
        wkL[h * 72 + d] = f32_to_bf16_rne(v);
    }
    if (tid < 48) { sumP[tid] = 0.f; sqP[tid] = 0.f; }
    __syncthreads();

    // ---- prologue stage 2: qt per (batch,h), B fragments ----
    if (tid < 384) {
        const int p = tid / 48, hh = tid % 48;
        float acc = 0.f;
        if (hh < NH) {
            acc = b_h[f * NH + hh];
            #pragma unroll 8
            for (int d = 0; d < ND; ++d)
                acc += qs[p][d] * (Wf[(ND + d) * NH + hh] + Wf[(2 * ND + d) * NH + hh]);
        }
        qts[p][hh] = acc;
    }
    short8 bfr[3][2];
    #pragma unroll
    for (int nt = 0; nt < 3; ++nt)
        #pragma unroll
        for (int ks = 0; ks < 2; ++ks)
            bfr[nt][ks] = *(const short8*)&wkL[(nt * 16 + col) * 72 + ks * 32 + quad * 8];
    __syncthreads();

    // ---- phase A: stream key (HBM, single pass), stats with qt folded in acc ----
    float s1[3] = {0.f, 0.f, 0.f}, s2[3] = {0.f, 0.f, 0.f};
    float4 Lb[2][2][4];   // [parity][tile][vec]

    auto load_tiles = [&](int j, float4 L[2][4]) {
        const float* kb = kb0 + (size_t)j * bstride;
        #pragma unroll
        for (int i = 0; i < 2; ++i) {
            const int mt = wv + 8 * i;
            if (mt <= 12) {
                const int s = 16 * mt + col;
                const float4* ptr = (const float4*)(kb + (size_t)(s < NS ? s : NS - 1) * ND + quad * 8);
                L[i][0] = ptr[0]; L[i][1] = ptr[1]; L[i][2] = ptr[8]; L[i][3] = ptr[9];
            }
        }
    };

    load_tiles(0, Lb[0]);
    for (int j = 0; j < 8; ++j) {
        if (j < 7) load_tiles(j + 1, Lb[(j + 1) & 1]);
        float4 (*L)[4] = Lb[j & 1];
        const float qv0 = qts[j][col], qv1 = qts[j][16 + col], qv2 = qts[j][32 + col];
        const float qv[3] = {qv0, qv1, qv2};
        #pragma unroll
        for (int i = 0; i < 2; ++i) {
            const int mt = wv + 8 * i;
            if (mt <= 12) {
                short8 fa = pack8(L[i][0], L[i][1]);
                short8 fb = pack8(L[i][2], L[i][3]);
                #pragma unroll
                for (int nt = 0; nt < 3; ++nt) {
                    f32x4 acc = {qv[nt], qv[nt], qv[nt], qv[nt]};
                    acc = __builtin_amdgcn_mfma_f32_16x16x32_bf16(fa, bfr[nt][0], acc, 0, 0, 0);
                    acc = __builtin_amdgcn_mfma_f32_16x16x32_bf16(fb, bfr[nt][1], acc, 0, 0, 0);
                    if (mt < 12) {
                        #pragma unroll
                        for (int r = 0; r < 4; ++r) { float v = acc[r]; s1[nt] += v; s2[nt] += v * v; }
                    } else {
                        const int base_s = 192 + quad * 4;
                        #pragma unroll
                        for (int r = 0; r < 4; ++r)
                            if (base_s + r < NS) { float v = acc[r]; s1[nt] += v; s2[nt] += v * v; }
                    }
                }
            }
        }
    }

    // stats reduce: shuffle over rows -> LDS atomics -> global atomics
    #pragma unroll
    for (int nt = 0; nt < 3; ++nt) {
        float a = s1[nt], c = s2[nt];
        a += __shfl_xor(a, 16, 64); a += __shfl_xor(a, 32, 64);
        c += __shfl_xor(c, 16, 64); c += __shfl_xor(c, 32, 64);
        if (quad == 0) {
            atomicAdd(&sumP[nt * 16 + col], a);
            atomicAdd(&sqP[nt * 16 + col], c);
        }
    }
    __syncthreads();
    if (tid < NH) {
        atomicAdd(&ws[WS_SUM + f * NH + tid], sumP[tid]);
        atomicAdd(&ws[WS_SQ  + f * NH + tid], sqP[tid]);
    }
    __syncthreads();

    // ---- grid barrier: 256 blocks, all co-resident (1 fits on every CU) ----
    if (tid == 0) {
        __threadfence();
        unsigned* cnt = (unsigned*)(ws + WS_BAR);
        __hip_atomic_fetch_add(cnt, 1u, __ATOMIC_ACQ_REL, __HIP_MEMORY_SCOPE_AGENT);
        while (__hip_atomic_load(cnt, __ATOMIC_ACQUIRE, __HIP_MEMORY_SCOPE_AGENT) < (unsigned)GRID_BLKS)
            __builtin_amdgcn_s_sleep(8);
    }
    __syncthreads();

    // ---- phase B: mean/var, per-pair scores/softmax/weighted-sum (key L3-hot) ----
    const float inv_n = 1.f / (float)(NB * NS);
    float mn[3], iv[3], wo[3];
    #pragma unroll
    for (int nt = 0; nt < 3; ++nt) {
        const int hh = nt * 16 + col;
        const bool hv = hh < NH;
        const int hc = hv ? hh : 0;
        const float sm = __hip_atomic_load(&ws[WS_SUM + f * NH + hc], __ATOMIC_RELAXED, __HIP_MEMORY_SCOPE_AGENT);
        const float sq = __hip_atomic_load(&ws[WS_SQ  + f * NH + hc], __ATOMIC_RELAXED, __HIP_MEMORY_SCOPE_AGENT);
        const float m = sm * inv_n;
        mn[nt] = m;
        iv[nt] = rsqrtf(fmaxf(sq * inv_n - m * m, 0.f) + EPSV);
        wo[nt] = hv ? W_o[f * NH + hh] : 0.f;
    }
    const float alf = alpha[f];
    const float bo = b_o[f];

    for (int j = 0; j < 8; ++j) {
        const int bfi = (b0 + j) * NF + f;
        const float* kb = kb0 + (size_t)j * bstride;
        const int sq_n = seqn[bfi];
        const float qv[3] = {qts[j][col], qts[j][16 + col], qts[j][32 + col]};

        short8 kah[2][2];
        #pragma unroll
        for (int i = 0; i < 2; ++i) {
            const int mt = wv + 8 * i;
            if (mt <= 12) {
                const int s = 16 * mt + col;
                const float4* ptr = (const float4*)(kb + (size_t)(s < NS ? s : NS - 1) * ND + quad * 8);
                float4 a0 = ptr[0], a1 = ptr[1], c0 = ptr[8], c1 = ptr[9];
                kah[i][0] = pack8(a0, a1);
                kah[i][1] = pack8(c0, c1);
                float part[4] = {0.f, 0.f, 0.f, 0.f};
                #pragma unroll
                for (int nt = 0; nt < 3; ++nt) {
                    f32x4 acc = {qv[nt], qv[nt], qv[nt], qv[nt]};
                    acc = __builtin_amdgcn_mfma_f32_16x16x32_bf16(kah[i][0], bfr[nt][0], acc, 0, 0, 0);
                    acc = __builtin_amdgcn_mfma_f32_16x16x32_bf16(kah[i][1], bfr[nt][1], acc, 0, 0, 0);
                    #pragma unroll
                    for (int r = 0; r < 4; ++r) {
                        const float h = acc[r];
                        const float pg = 1.f / (1.f + __expf(-(h - mn[nt]) * iv[nt]));
                        part[r] += (alf + (1.f - alf) * pg) * h * wo[nt];
                    }
                }
                #pragma unroll
                for (int r = 0; r < 4; ++r) {
                    float v = part[r];
                    v += __shfl_xor(v, 1, 64); v += __shfl_xor(v, 2, 64);
                    v += __shfl_xor(v, 4, 64); v += __shfl_xor(v, 8, 64);
                    const int srow = 16 * mt + quad * 4 + r;
                    if (col == 0 && srow < NS) sw[srow] = v + bo;
                }
            }
        }
        __syncthreads();

        // softmax over s (8-wave)
        const bool valid = (tid < NS) && (tid < sq_n);
        const float sc = valid ? sw[tid] : -1e30f;
        float m = sc;
        m = fmaxf(m, __shfl_xor(m, 1, 64));  m = fmaxf(m, __shfl_xor(m, 2, 64));
        m = fmaxf(m, __shfl_xor(m, 4, 64));  m = fmaxf(m, __shfl_xor(m, 8, 64));
        m = fmaxf(m, __shfl_xor(m, 16, 64)); m = fmaxf(m, __shfl_xor(m, 32, 64));
        if (lane == 0) redM[wv] = m;
        __syncthreads();
        float maxv = redM[0];
        #pragma unroll
        for (int w = 1; w < 8; ++w) maxv = fmaxf(maxv, redM[w]);
        const float e = valid ? __expf(sc - maxv) : 0.f;
        float l = e;
        l += __shfl_xor(l, 1, 64);  l += __shfl_xor(l, 2, 64);
        l += __shfl_xor(l, 4, 64);  l += __shfl_xor(l, 8, 64);
        l += __shfl_xor(l, 16, 64); l += __shfl_xor(l, 32, 64);
        if (lane == 0) redS[wv] = l;
        __syncthreads();
        float tot = redS[0];
        #pragma unroll
        for (int w = 1; w < 8; ++w) tot += redS[w];
        const float isum = 1.f / tot;
        if (tid < 208) sw[tid] = e * isum;   // rows >= 200 get 0
        __syncthreads();

        // out = attn @ key from retained bf16 fragments
        float po0[8] = {0,0,0,0,0,0,0,0}, po1[8] = {0,0,0,0,0,0,0,0};
        #pragma unroll
        for (int i = 0; i < 2; ++i) {
            const int mt = wv + 8 * i;
            if (mt <= 12) {
                const float w = sw[16 * mt + col];
                #pragma unroll
                for (int jj = 0; jj < 8; ++jj) {
                    po0[jj] += w * bf16_to_f32((unsigned short)kah[i][0][jj]);
                    po1[jj] += w * bf16_to_f32((unsigned short)kah[i][1][jj]);
                }
            }
        }
        #pragma unroll
        for (int off = 1; off <= 8; off <<= 1) {
            #pragma unroll
            for (int jj = 0; jj < 8; ++jj) {
                po0[jj] += __shfl_xor(po0[jj], off, 64);
                po1[jj] += __shfl_xor(po1[jj], off, 64);
            }
        }
        if (col == 0) {
            #pragma unroll
            for (int jj = 0; jj < 8; ++jj) {
                pout[wv][quad * 8 + jj] = po0[jj];
                pout[wv][32 + quad * 8 + jj] = po1[jj];
            }
        }
        __syncthreads();
        if (tid < 64) {
            float o = 0.f;
            #pragma unroll
            for (int w = 0; w < 8; ++w) o += pout[w][tid];
            out[(size_t)bfi * ND + tid] = o;
        }
        __syncthreads();
    }
}

extern "C" void kernel_launch(void* const* d_in, const int* in_sizes, int n_in,
                              void* d_out, int out_size, void* d_ws, size_t ws_size,
                              hipStream_t stream) {
    const float* query = (const float*)d_in[0];
    const float* key   = (const float*)d_in[1];
    const float* W_h   = (const float*)d_in[2];
    const float* b_h   = (const float*)d_in[3];
    const float* alpha = (const float*)d_in[4];
    const float* W_o   = (const float*)d_in[5];
    const float* b_o   = (const float*)d_in[6];
    const int*   seqn  = (const int*)d_in[7];
    float* out = (float*)d_out;
    float* ws  = (float*)d_ws;

    hipMemsetAsync(ws, 0, 578 * sizeof(float), stream);  // sum/sumsq + barrier counter
    k_fused<<<GRID_BLKS, 512, 0, stream>>>(query, key, W_h, b_h, alpha, W_o, b_o, seqn, ws, out);
}

// Round 7
// 225.720 us; speedup vs baseline: 1.1073x; 1.1073x over previous
//
#include <hip/hip_runtime.h>
#include <math.h>

#define NB 256
#define NF 8
#define NS 200
#define ND 64
#define NH 36
#define EPSV 1e-3f

// ws float-offset layout: [0,288) sum | [288,576) sumsq | [1152,...) qt[b*NF+f][48]
#define WS_SUM 0
#define WS_SQ  288
#define WS_QT  1152

typedef __attribute__((ext_vector_type(8))) short short8;
typedef __attribute__((ext_vector_type(4))) float f32x4;
typedef __attribute__((ext_vector_type(4))) int int4v;

__device__ __forceinline__ unsigned short f32_to_bf16_rne(float x) {
    unsigned u = __float_as_uint(x);
    unsigned r = u + 0x7FFFu + ((u >> 16) & 1u);
    return (unsigned short)(r >> 16);
}
// 8 floats -> 8 bf16 (truncation) via 4 v_perm_b32 (validated round 4+).
__device__ __forceinline__ short8 pack8(float4 a, float4 b) {
    int4v t;
    t[0] = (int)__builtin_amdgcn_perm(__float_as_uint(a.y), __float_as_uint(a.x), 0x07060302u);
    t[1] = (int)__builtin_amdgcn_perm(__float_as_uint(a.w), __float_as_uint(a.z), 0x07060302u);
    t[2] = (int)__builtin_amdgcn_perm(__float_as_uint(b.y), __float_as_uint(b.x), 0x07060302u);
    t[3] = (int)__builtin_amdgcn_perm(__float_as_uint(b.w), __float_as_uint(b.z), 0x07060302u);
    return __builtin_bit_cast(short8, t);
}

// grid 2048 (one (b,f) per block), 128 thr, 8 blocks/CU -> 16 waves/CU.
__global__ __launch_bounds__(128, 4) void k_stats(
    const float* __restrict__ query, const float* __restrict__ key,
    const float* __restrict__ W_h, const float* __restrict__ b_h,
    float* __restrict__ ws)
{
    const int blk = blockIdx.x;
    const int f = blk & (NF - 1);
    const int tid = threadIdx.x;
    const int lane = tid & 63, wv = tid >> 6;
    const int col = lane & 15, quad = lane >> 4;

    __shared__ __align__(16) unsigned short wkL[48 * 72];
    __shared__ float qsL[64];
    __shared__ float qtL[48];
    __shared__ float s1L[2][48], s2L[2][48];

    const float* Wf = W_h + (size_t)f * (3 * ND * NH);
    const float* kbase = key + (size_t)blk * (NS * ND);

    // issue first tile's loads (mt = wv) before any LDS work
    float4 cur[4], nxt[4];
    {
        const int s = min(16 * wv + col, NS - 1);
        const float4* p = (const float4*)(kbase + (size_t)s * ND + quad * 8);
        cur[0] = p[0]; cur[1] = p[1]; cur[2] = p[8]; cur[3] = p[9];
    }
    if (tid < 64) qsL[tid] = query[(size_t)blk * ND + tid];
    for (int i = tid; i < 48 * 64; i += 128) {
        int h = i >> 6, d = i & 63;
        float v = (h < NH) ? (Wf[d * NH + h] - Wf[(2 * ND + d) * NH + h]) : 0.f;
        wkL[h * 72 + d] = f32_to_bf16_rne(v);
    }
    __syncthreads();

    short8 bfr[3][2];
    #pragma unroll
    for (int nt = 0; nt < 3; ++nt)
        #pragma unroll
        for (int ks = 0; ks < 2; ++ks)
            bfr[nt][ks] = *(const short8*)&wkL[(nt * 16 + col) * 72 + ks * 32 + quad * 8];

    // stream tiles mt = wv + 2t, t=0..6 (wv1's mt=13 fully masked), depth-1 prefetch
    float s1[3] = {0.f, 0.f, 0.f}, s2[3] = {0.f, 0.f, 0.f};
    #pragma unroll
    for (int t = 0; t < 7; ++t) {
        const int mt = wv + 2 * t;
        if (t < 6) {
            const int sn = min(16 * (mt + 2) + col, NS - 1);
            const float4* p = (const float4*)(kbase + (size_t)sn * ND + quad * 8);
            nxt[0] = p[0]; nxt[1] = p[1]; nxt[2] = p[8]; nxt[3] = p[9];
        }
        const short8 fa = pack8(cur[0], cur[1]);
        const short8 fb = pack8(cur[2], cur[3]);
        const int base_s = 16 * mt + quad * 4;
        #pragma unroll
        for (int nt = 0; nt < 3; ++nt) {
            f32x4 acc = {0.f, 0.f, 0.f, 0.f};
            acc = __builtin_amdgcn_mfma_f32_16x16x32_bf16(fa, bfr[nt][0], acc, 0, 0, 0);
            acc = __builtin_amdgcn_mfma_f32_16x16x32_bf16(fb, bfr[nt][1], acc, 0, 0, 0);
            #pragma unroll
            for (int r = 0; r < 4; ++r) {
                const float v = (base_s + r < NS) ? acc[r] : 0.f;
                s1[nt] += v; s2[nt] += v * v;
            }
        }
        cur[0] = nxt[0]; cur[1] = nxt[1]; cur[2] = nxt[2]; cur[3] = nxt[3];
    }

    // qt (wave-1 side job; W2/W3 are L2-hot)
    if (tid >= 64 && tid < 64 + NH) {
        const int h = tid - 64;
        float acc = b_h[f * NH + h];
        #pragma unroll 8
        for (int d = 0; d < ND; ++d)
            acc += qsL[d] * (Wf[(ND + d) * NH + h] + Wf[(2 * ND + d) * NH + h]);
        qtL[h] = acc;
        ws[WS_QT + (size_t)blk * 48 + h] = acc;
    }
    if (tid >= 64 + NH && tid < 64 + 48)
        ws[WS_QT + (size_t)blk * 48 + (tid - 64)] = 0.f;   // zero-pad h in [36,48)

    // reduce: shuffle over s-rows -> LDS -> qt-folded global atomics
    #pragma unroll
    for (int nt = 0; nt < 3; ++nt) {
        float a = s1[nt], c = s2[nt];
        a += __shfl_xor(a, 16, 64); a += __shfl_xor(a, 32, 64);
        c += __shfl_xor(c, 16, 64); c += __shfl_xor(c, 32, 64);
        if (quad == 0) { s1L[wv][nt * 16 + col] = a; s2L[wv][nt * 16 + col] = c; }
    }
    __syncthreads();
    if (tid < NH) {
        const float S1 = s1L[0][tid] + s1L[1][tid];
        const float S2 = s2L[0][tid] + s2L[1][tid];
        const float qt = qtL[tid];
        atomicAdd(&ws[WS_SUM + f * NH + tid], S1 + 200.f * qt);
        atomicAdd(&ws[WS_SQ  + f * NH + tid], S2 + 2.f * qt * S1 + 200.f * qt * qt);
    }
}

// grid 2048, 128 thr, 8 blocks/CU. Key is L3-hot after k_stats.
__global__ __launch_bounds__(128, 4) void k_attn(
    const float* __restrict__ key, const float* __restrict__ W_h,
    const float* __restrict__ alpha, const float* __restrict__ W_o,
    const float* __restrict__ b_o, const int* __restrict__ seqn,
    const float* __restrict__ ws, float* __restrict__ out)
{
    const int blk = blockIdx.x;
    const int f = blk & (NF - 1);
    const int tid = threadIdx.x;
    const int lane = tid & 63, wv = tid >> 6;
    const int col = lane & 15, quad = lane >> 4;

    __shared__ __align__(16) unsigned short wkL[48 * 72];
    __shared__ float swL[208];
    __shared__ float redA[2], redB[2];
    __shared__ float poutL[2][64];

    const float* Wf = W_h + (size_t)f * (3 * ND * NH);
    const float* kbase = key + (size_t)blk * (NS * ND);

    float4 cur[4], nxt[4];
    {
        const int s = min(16 * wv + col, NS - 1);
        const float4* p = (const float4*)(kbase + (size_t)s * ND + quad * 8);
        cur[0] = p[0]; cur[1] = p[1]; cur[2] = p[8]; cur[3] = p[9];
    }
    for (int i = tid; i < 48 * 64; i += 128) {
        int h = i >> 6, d = i & 63;
        float v = (h < NH) ? (Wf[d * NH + h] - Wf[(2 * ND + d) * NH + h]) : 0.f;
        wkL[h * 72 + d] = f32_to_bf16_rne(v);
    }
    __syncthreads();

    short8 bfr[3][2];
    #pragma unroll
    for (int nt = 0; nt < 3; ++nt)
        #pragma unroll
        for (int ks = 0; ks < 2; ++ks)
            bfr[nt][ks] = *(const short8*)&wkL[(nt * 16 + col) * 72 + ks * 32 + quad * 8];

    const float inv_n = 1.f / (float)(NB * NS);
    float qv[3], mn[3], iv[3], wo[3];
    #pragma unroll
    for (int nt = 0; nt < 3; ++nt) {
        const int hh = nt * 16 + col;
        const bool hv = hh < NH;
        const int hc = hv ? hh : 0;
        qv[nt] = ws[WS_QT + (size_t)blk * 48 + hh];
        const float sm = ws[WS_SUM + f * NH + hc];
        const float sq = ws[WS_SQ  + f * NH + hc];
        const float m = sm * inv_n;
        mn[nt] = m;
        iv[nt] = rsqrtf(fmaxf(sq * inv_n - m * m, 0.f) + EPSV);
        wo[nt] = hv ? W_o[f * NH + hh] : 0.f;
    }
    const float alf = alpha[f];
    const float bo = b_o[f];
    const int sq_n = seqn[blk];

    // score pass, depth-1 prefetch
    #pragma unroll
    for (int t = 0; t < 7; ++t) {
        const int mt = wv + 2 * t;
        if (t < 6) {
            const int sn = min(16 * (mt + 2) + col, NS - 1);
            const float4* p = (const float4*)(kbase + (size_t)sn * ND + quad * 8);
            nxt[0] = p[0]; nxt[1] = p[1]; nxt[2] = p[8]; nxt[3] = p[9];
        }
        const short8 fa = pack8(cur[0], cur[1]);
        const short8 fb = pack8(cur[2], cur[3]);
        float part[4] = {0.f, 0.f, 0.f, 0.f};
        #pragma unroll
        for (int nt = 0; nt < 3; ++nt) {
            f32x4 acc = {qv[nt], qv[nt], qv[nt], qv[nt]};
            acc = __builtin_amdgcn_mfma_f32_16x16x32_bf16(fa, bfr[nt][0], acc, 0, 0, 0);
            acc = __builtin_amdgcn_mfma_f32_16x16x32_bf16(fb, bfr[nt][1], acc, 0, 0, 0);
            #pragma unroll
            for (int r = 0; r < 4; ++r) {
                const float h = acc[r];
                const float pg = 1.f / (1.f + __expf(-(h - mn[nt]) * iv[nt]));
                part[r] += (alf + (1.f - alf) * pg) * h * wo[nt];
            }
        }
        #pragma unroll
        for (int r = 0; r < 4; ++r) {
            float v = part[r];
            v += __shfl_xor(v, 1, 64); v += __shfl_xor(v, 2, 64);
            v += __shfl_xor(v, 4, 64); v += __shfl_xor(v, 8, 64);
            const int srow = 16 * mt + quad * 4 + r;
            if (col == 0 && srow < NS) swL[srow] = v + bo;
        }
        cur[0] = nxt[0]; cur[1] = nxt[1]; cur[2] = nxt[2]; cur[3] = nxt[3];
    }
    __syncthreads();

    // softmax (each thread owns scores tid and tid+128)
    const int i2 = tid + 128;
    const float v1 = (tid < sq_n) ? swL[tid] : -1e30f;
    const float v2 = (i2 < NS && i2 < sq_n) ? swL[i2] : -1e30f;
    float m = fmaxf(v1, v2);
    m = fmaxf(m, __shfl_xor(m, 1, 64));  m = fmaxf(m, __shfl_xor(m, 2, 64));
    m = fmaxf(m, __shfl_xor(m, 4, 64));  m = fmaxf(m, __shfl_xor(m, 8, 64));
    m = fmaxf(m, __shfl_xor(m, 16, 64)); m = fmaxf(m, __shfl_xor(m, 32, 64));
    if (lane == 0) redA[wv] = m;
    __syncthreads();
    const float maxv = fmaxf(redA[0], redA[1]);
    const float e1 = (tid < sq_n) ? __expf(v1 - maxv) : 0.f;
    const float e2 = (i2 < NS && i2 < sq_n) ? __expf(v2 - maxv) : 0.f;
    float l = e1 + e2;
    l += __shfl_xor(l, 1, 64);  l += __shfl_xor(l, 2, 64);
    l += __shfl_xor(l, 4, 64);  l += __shfl_xor(l, 8, 64);
    l += __shfl_xor(l, 16, 64); l += __shfl_xor(l, 32, 64);
    if (lane == 0) redB[wv] = l;
    __syncthreads();
    const float isum = 1.f / (redB[0] + redB[1]);
    swL[tid] = e1 * isum;
    if (i2 < 208) swL[i2] = e2 * isum;   // rows 200..207 -> 0
    __syncthreads();

    // out = attn @ key (fp32 reload, L2-hot; wave w covers s in [w*100, w*100+100))
    {
        const int d = lane;
        float acc = 0.f;
        const int s0 = wv * 100;
        #pragma unroll 10
        for (int s = s0; s < s0 + 100; ++s)
            acc += swL[s] * kbase[(size_t)s * ND + d];
        poutL[wv][d] = acc;
    }
    __syncthreads();
    if (tid < 64)
        out[(size_t)blk * ND + tid] = poutL[0][tid] + poutL[1][tid];
}

extern "C" void kernel_launch(void* const* d_in, const int* in_sizes, int n_in,
                              void* d_out, int out_size, void* d_ws, size_t ws_size,
                              hipStream_t stream) {
    const float* query = (const float*)d_in[0];
    const float* key   = (const float*)d_in[1];
    const float* W_h   = (const float*)d_in[2];
    const float* b_h   = (const float*)d_in[3];
    const float* alpha = (const float*)d_in[4];
    const float* W_o   = (const float*)d_in[5];
    const float* b_o   = (const float*)d_in[6];
    const int*   seqn  = (const int*)d_in[7];
    float* out = (float*)d_out;
    float* ws  = (float*)d_ws;

    hipMemsetAsync(ws, 0, 576 * sizeof(float), stream);   // zero sum/sumsq
    k_stats<<<NB * NF, 128, 0, stream>>>(query, key, W_h, b_h, ws);
    k_attn<<<NB * NF, 128, 0, stream>>>(key, W_h, alpha, W_o, b_o, seqn, ws, out);
}

// Round 8
// 222.125 us; speedup vs baseline: 1.1253x; 1.0162x over previous
//
#include <hip/hip_runtime.h>
#include <math.h>

#define NB 256
#define NF 8
#define NS 200
#define ND 64
#define NH 36
#define EPSV 1e-3f

// ws float-offset layout (no zero-init required anywhere):
#define WS_SUM 0                    // [0,288)   reduced sum  (written by k_reduce)
#define WS_SQ  288                  // [288,576) reduced sumsq
#define WS_QT  4096                 // qt[b*NF+f][48]  (2048*48)
#define WS_P   102400               // P[(f*72)+j][256] partials, j<36: S1(h), j>=36: S2(h-36)

typedef __attribute__((ext_vector_type(8))) short short8;
typedef __attribute__((ext_vector_type(4))) float f32x4;

__device__ __forceinline__ unsigned short f32_to_bf16_rne(float x) {
    unsigned u = __float_as_uint(x);
    unsigned r = u + 0x7FFFu + ((u >> 16) & 1u);
    return (unsigned short)(r >> 16);
}
// two floats -> one dword holding [bf16(x) | bf16(y)<<16] (truncation)
__device__ __forceinline__ unsigned pack2(float x, float y) {
    return __builtin_amdgcn_perm(__float_as_uint(y), __float_as_uint(x), 0x07060302u);
}

// Stage 200x64 key rows (fp32 global, LANE-CONTIGUOUS) -> bf16 LDS tile, stride 72.
// 256 threads; wave w owns rows [50w, 50w+50). Rows 200..207 zeroed.
__device__ __forceinline__ void stage_key(const float* kbase, unsigned short* kL,
                                          int tid, int lane, int wv) {
    const float4* kb4 = (const float4*)kbase;   // 3200 float4, 16 per row
    const int base = wv * 800;
    #pragma unroll
    for (int j = 0; j < 13; ++j) {
        const int idx = base + j * 64 + lane;
        const bool ok = (j < 12) | (lane < 32);
        const float4 v = kb4[ok ? idx : base];
        if (ok) {
            const int r = idx >> 4, dc = idx & 15;
            unsigned t0 = pack2(v.x, v.y), t1 = pack2(v.z, v.w);
            uint2 u; u.x = t0; u.y = t1;
            *(uint2*)&kL[r * 72 + dc * 4] = u;
        }
    }
    for (int i = tid; i < 288; i += 256) ((unsigned*)&kL[200 * 72])[i] = 0u;
}

__global__ __launch_bounds__(256, 4) void k_stats(
    const float* __restrict__ query, const float* __restrict__ key,
    const float* __restrict__ W_h, const float* __restrict__ b_h,
    float* __restrict__ ws)
{
    const int blk = blockIdx.x;            // = b*NF + f
    const int f = blk & (NF - 1);
    const int b = blk >> 3;
    const int tid = threadIdx.x;
    const int lane = tid & 63, wv = tid >> 6;
    const int col = lane & 15, quad = lane >> 4;

    __shared__ __align__(16) unsigned short kL[208 * 72];
    __shared__ __align__(16) unsigned short wkL[48 * 72];
    __shared__ float qsL[64], qtL[48];
    __shared__ float s1L[4][48], s2L[4][48];

    const float* Wf = W_h + (size_t)f * (3 * ND * NH);
    const float* kbase = key + (size_t)blk * (NS * ND);

    stage_key(kbase, kL, tid, lane, wv);
    if (tid < 64) qsL[tid] = query[(size_t)blk * ND + tid];
    for (int i = tid; i < 48 * 64; i += 256) {
        int h = i >> 6, d = i & 63;
        float v = (h < NH) ? (Wf[d * NH + h] - Wf[(2 * ND + d) * NH + h]) : 0.f;
        wkL[h * 72 + d] = f32_to_bf16_rne(v);
    }
    __syncthreads();

    short8 bfr[3][2];
    #pragma unroll
    for (int nt = 0; nt < 3; ++nt)
        #pragma unroll
        for (int ks = 0; ks < 2; ++ks)
            bfr[nt][ks] = *(const short8*)&wkL[(nt * 16 + col) * 72 + ks * 32 + quad * 8];

    float s1[3] = {0.f, 0.f, 0.f}, s2[3] = {0.f, 0.f, 0.f};
    for (int mt = wv; mt < 13; mt += 4) {
        const short8 fa = *(const short8*)&kL[(16 * mt + col) * 72 + quad * 8];
        const short8 fb = *(const short8*)&kL[(16 * mt + col) * 72 + 32 + quad * 8];
        const int base_s = 16 * mt + quad * 4;
        #pragma unroll
        for (int nt = 0; nt < 3; ++nt) {
            f32x4 acc = {0.f, 0.f, 0.f, 0.f};
            acc = __builtin_amdgcn_mfma_f32_16x16x32_bf16(fa, bfr[nt][0], acc, 0, 0, 0);
            acc = __builtin_amdgcn_mfma_f32_16x16x32_bf16(fb, bfr[nt][1], acc, 0, 0, 0);
            #pragma unroll
            for (int r = 0; r < 4; ++r) {
                const float v = (base_s + r < NS) ? acc[r] : 0.f;
                s1[nt] += v; s2[nt] += v * v;
            }
        }
    }

    // qt side-job on wave 1 lanes 0..35 (W2/W3 L2-hot)
    if (tid >= 64 && tid < 64 + NH) {
        const int h = tid - 64;
        float acc = b_h[f * NH + h];
        #pragma unroll 8
        for (int d = 0; d < ND; ++d)
            acc += qsL[d] * (Wf[(ND + d) * NH + h] + Wf[(2 * ND + d) * NH + h]);
        qtL[h] = acc;
        ws[WS_QT + (size_t)blk * 48 + h] = acc;
    }
    if (tid >= 64 + NH && tid < 64 + 48)
        ws[WS_QT + (size_t)blk * 48 + (tid - 64)] = 0.f;

    #pragma unroll
    for (int nt = 0; nt < 3; ++nt) {
        float a = s1[nt], c = s2[nt];
        a += __shfl_xor(a, 16, 64); a += __shfl_xor(a, 32, 64);
        c += __shfl_xor(c, 16, 64); c += __shfl_xor(c, 32, 64);
        if (quad == 0) { s1L[wv][nt * 16 + col] = a; s2L[wv][nt * 16 + col] = c; }
    }
    __syncthreads();
    if (tid < NH) {
        const float S1 = s1L[0][tid] + s1L[1][tid] + s1L[2][tid] + s1L[3][tid];
        const float S2 = s2L[0][tid] + s2L[1][tid] + s2L[2][tid] + s2L[3][tid];
        const float qt = qtL[tid];
        ws[WS_P + (size_t)(f * 72 + tid) * 256 + b]      = S1 + 200.f * qt;
        ws[WS_P + (size_t)(f * 72 + 36 + tid) * 256 + b] = S2 + 2.f * qt * S1 + 200.f * qt * qt;
    }
}

// 576 blocks x 64 threads: sum P[j][0..255] -> SUM/SQ
__global__ __launch_bounds__(64) void k_reduce(float* __restrict__ ws) {
    const int j = blockIdx.x;              // f*72 + jj
    const int lane = threadIdx.x;
    const float4 v = ((const float4*)&ws[WS_P + (size_t)j * 256])[lane];
    float s = v.x + v.y + v.z + v.w;
    s += __shfl_xor(s, 1, 64);  s += __shfl_xor(s, 2, 64);
    s += __shfl_xor(s, 4, 64);  s += __shfl_xor(s, 8, 64);
    s += __shfl_xor(s, 16, 64); s += __shfl_xor(s, 32, 64);
    if (lane == 0) {
        const int f = j / 72, jj = j % 72;
        if (jj < NH) ws[WS_SUM + f * NH + jj] = s;
        else         ws[WS_SQ  + f * NH + (jj - NH)] = s;
    }
}

__global__ __launch_bounds__(256, 4) void k_attn(
    const float* __restrict__ key, const float* __restrict__ W_h,
    const float* __restrict__ alpha, const float* __restrict__ W_o,
    const float* __restrict__ b_o, const int* __restrict__ seqn,
    const float* __restrict__ ws, float* __restrict__ out)
{
    const int blk = blockIdx.x;
    const int f = blk & (NF - 1);
    const int tid = threadIdx.x;
    const int lane = tid & 63, wv = tid >> 6;
    const int col = lane & 15, quad = lane >> 4;

    __shared__ __align__(16) unsigned short kL[208 * 72];
    __shared__ __align__(16) unsigned short wkL[48 * 72];
    __shared__ float swL[208];
    __shared__ float redA[4], redB[4];
    __shared__ float poutL[8][64];

    const float* Wf = W_h + (size_t)f * (3 * ND * NH);
    const float* kbase = key + (size_t)blk * (NS * ND);

    stage_key(kbase, kL, tid, lane, wv);
    for (int i = tid; i < 48 * 64; i += 256) {
        int h = i >> 6, d = i & 63;
        float v = (h < NH) ? (Wf[d * NH + h] - Wf[(2 * ND + d) * NH + h]) : 0.f;
        wkL[h * 72 + d] = f32_to_bf16_rne(v);
    }
    __syncthreads();

    short8 bfr[3][2];
    #pragma unroll
    for (int nt = 0; nt < 3; ++nt)
        #pragma unroll
        for (int ks = 0; ks < 2; ++ks)
            bfr[nt][ks] = *(const short8*)&wkL[(nt * 16 + col) * 72 + ks * 32 + quad * 8];

    const float inv_n = 1.f / (float)(NB * NS);
    float qv[3], mn[3], iv[3], wo[3];
    #pragma unroll
    for (int nt = 0; nt < 3; ++nt) {
        const int hh = nt * 16 + col;
        const bool hv = hh < NH;
        const int hc = hv ? hh : 0;
        qv[nt] = ws[WS_QT + (size_t)blk * 48 + hh];
        const float sm = ws[WS_SUM + f * NH + hc];
        const float sq = ws[WS_SQ  + f * NH + hc];
        const float m = sm * inv_n;
        mn[nt] = m;
        iv[nt] = rsqrtf(fmaxf(sq * inv_n - m * m, 0.f) + EPSV);
        wo[nt] = hv ? W_o[f * NH + hh] : 0.f;
    }
    const float alf = alpha[f];
    const float bo = b_o[f];
    const int sq_n = seqn[blk];

    for (int mt = wv; mt < 13; mt += 4) {
        const short8 fa = *(const short8*)&kL[(16 * mt + col) * 72 + quad * 8];
        const short8 fb = *(const short8*)&kL[(16 * mt + col) * 72 + 32 + quad * 8];
        float part[4] = {0.f, 0.f, 0.f, 0.f};
        #pragma unroll
        for (int nt = 0; nt < 3; ++nt) {
            f32x4 acc = {qv[nt], qv[nt], qv[nt], qv[nt]};
            acc = __builtin_amdgcn_mfma_f32_16x16x32_bf16(fa, bfr[nt][0], acc, 0, 0, 0);
            acc = __builtin_amdgcn_mfma_f32_16x16x32_bf16(fb, bfr[nt][1], acc, 0, 0, 0);
            #pragma unroll
            for (int r = 0; r < 4; ++r) {
                const float h = acc[r];
                const float pg = 1.f / (1.f + __expf(-(h - mn[nt]) * iv[nt]));
                part[r] += (alf + (1.f - alf) * pg) * h * wo[nt];
            }
        }
        #pragma unroll
        for (int r = 0; r < 4; ++r) {
            float v = part[r];
            v += __shfl_xor(v, 1, 64); v += __shfl_xor(v, 2, 64);
            v += __shfl_xor(v, 4, 64); v += __shfl_xor(v, 8, 64);
            const int srow = 16 * mt + quad * 4 + r;
            if (col == 0 && srow < NS) swL[srow] = v + bo;
        }
    }
    __syncthreads();

    // softmax over s (200 scores, one per thread tid<200)
    const bool valid = (tid < NS) && (tid < sq_n);
    const float sc = valid ? swL[tid] : -1e30f;
    float m = sc;
    m = fmaxf(m, __shfl_xor(m, 1, 64));  m = fmaxf(m, __shfl_xor(m, 2, 64));
    m = fmaxf(m, __shfl_xor(m, 4, 64));  m = fmaxf(m, __shfl_xor(m, 8, 64));
    m = fmaxf(m, __shfl_xor(m, 16, 64)); m = fmaxf(m, __shfl_xor(m, 32, 64));
    if (lane == 0) redA[wv] = m;
    __syncthreads();
    const float maxv = fmaxf(fmaxf(redA[0], redA[1]), fmaxf(redA[2], redA[3]));
    const float e = valid ? __expf(sc - maxv) : 0.f;
    float l = e;
    l += __shfl_xor(l, 1, 64);  l += __shfl_xor(l, 2, 64);
    l += __shfl_xor(l, 4, 64);  l += __shfl_xor(l, 8, 64);
    l += __shfl_xor(l, 16, 64); l += __shfl_xor(l, 32, 64);
    if (lane == 0) redB[wv] = l;
    __syncthreads();
    const float isum = 1.f / (redB[0] + redB[1] + redB[2] + redB[3]);
    if (tid < NS) swL[tid] = e * isum;
    __syncthreads();

    // out = attn @ key from bf16 LDS tile; 8 groups x 25 rows
    {
        const int g = wv * 2 + (lane >> 5);
        const int c = lane & 31;              // owns d = 2c, 2c+1
        float a0 = 0.f, a1 = 0.f;
        const int s0 = g * 25;
        #pragma unroll 5
        for (int s = s0; s < s0 + 25; ++s) {
            const unsigned w2 = *(const unsigned*)&kL[s * 72 + 2 * c];
            const float wgt = swL[s];
            a0 += wgt * __uint_as_float(w2 << 16);
            a1 += wgt * __uint_as_float(w2 & 0xFFFF0000u);
        }
        poutL[g][2 * c]     = a0;
        poutL[g][2 * c + 1] = a1;
    }
    __syncthreads();
    if (tid < 64) {
        float o = 0.f;
        #pragma unroll
        for (int g = 0; g < 8; ++g) o += poutL[g][tid];
        out[(size_t)blk * ND + tid] = o;
    }
}

extern "C" void kernel_launch(void* const* d_in, const int* in_sizes, int n_in,
                              void* d_out, int out_size, void* d_ws, size_t ws_size,
                              hipStream_t stream) {
    const float* query = (const float*)d_in[0];
    const float* key   = (const float*)d_in[1];
    const float* W_h   = (const float*)d_in[2];
    const float* b_h   = (const float*)d_in[3];
    const float* alpha = (const float*)d_in[4];
    const float* W_o   = (const float*)d_in[5];
    const float* b_o   = (const float*)d_in[6];
    const int*   seqn  = (const int*)d_in[7];
    float* out = (float*)d_out;
    float* ws  = (float*)d_ws;

    k_stats<<<NB * NF, 256, 0, stream>>>(query, key, W_h, b_h, ws);
    k_reduce<<<576, 64, 0, stream>>>(ws);
    k_attn<<<NB * NF, 256, 0, stream>>>(key, W_h, alpha, W_o, b_o, seqn, ws, out);
}